// Round 3
// baseline (76.636 us; speedup 1.0000x reference)
//
#include <hip/hip_runtime.h>
#include <math.h>

// Problem constants: N=4, M=64, A=64, O=5, F=256
// Reassociated computation:
//   Sc5[n, a*5+o, b*5+p]  (320x320 per n)   -- 5x bilinear+swish, filt, idx-expand
//   coup[n,m,b,k] = Y_k(unit(R)) * ||C[n,m,b,:]||
//   H[c=b*5+p][i] = sum_k coup[b][k] * cgc[k][i][seg[p]],  seg=[0,0,1,2,3]
//   W[r][i]   = sum_c Sc5[n][r][c] * H[c][i]
//   coeff[r][i] = C[n,m,r] * W[r][i]
//   out[n,m,f,i] = sum_r coeff[r][i] * ao[n,m,r,f]

__global__ void k_sc(const float* __restrict__ S, const float* __restrict__ wst,
                     float* __restrict__ SC) {
    int t = blockIdx.x * 256 + threadIdx.x;   // 16384 threads total
    int n = t >> 12;
    int i = (t >> 6) & 63;
    int j = t & 63;
    float M[3][3];
#pragma unroll
    for (int x = 0; x < 3; ++x)
#pragma unroll
        for (int y = 0; y < 3; ++y)
            M[x][y] = S[(((n * 64 + i) * 3 + x) * 64 + j) * 3 + y];
#pragma unroll
    for (int it = 0; it < 5; ++it) {
        float w[3][3];
#pragma unroll
        for (int a = 0; a < 3; ++a)
#pragma unroll
            for (int b = 0; b < 3; ++b)
                w[a][b] = wst[it * 9 + a * 3 + b];
        float T[3][3];
#pragma unroll
        for (int a = 0; a < 3; ++a)
#pragma unroll
            for (int d = 0; d < 3; ++d)
                T[a][d] = w[a][0] * M[0][d] + w[a][1] * M[1][d] + w[a][2] * M[2][d];
#pragma unroll
        for (int a = 0; a < 3; ++a)
#pragma unroll
            for (int c = 0; c < 3; ++c) {
                float v = T[a][0] * w[c][0] + T[a][1] * w[c][1] + T[a][2] * w[c][2];
                M[a][c] = v / (1.f + expf(-v));   // swish
            }
    }
    // filt = [[1,1,0],[1,1,0],[0,0,1]]
    M[0][2] = 0.f; M[1][2] = 0.f; M[2][0] = 0.f; M[2][1] = 0.f;
    const int idx5[5] = {0, 1, 2, 2, 2};
    float* dst = SC + (size_t)n * 320 * 320 + (size_t)(i * 5) * 320 + j * 5;
#pragma unroll
    for (int o = 0; o < 5; ++o)
#pragma unroll
        for (int p = 0; p < 5; ++p)
            dst[o * 320 + p] = M[idx5[o]][idx5[p]];
}

__global__ __launch_bounds__(512) void k_main(
        const float* __restrict__ ao, const float* __restrict__ C,
        const float* __restrict__ R, const float* __restrict__ cgc,
        const float* __restrict__ SC, float* __restrict__ out) {
    __shared__ float s_coup[64][9];
    __shared__ float s_cgc[729];
    __shared__ float s_H2[320][9];
    __shared__ float s_coeff[320][9];
    __shared__ float s_red[256][9];

    const int bid = blockIdx.x;        // n*64 + m
    const int n = bid >> 6;
    const int tid = threadIdx.x;

    // load cgc
    for (int o = tid; o < 729; o += 512) s_cgc[o] = cgc[o];

    // coup[b][k] = Y_k(unit(R)) * ||C||
    if (tid < 64) {
        const int b = tid;
        const float* rp = R + ((size_t)bid * 64 + b) * 3;
        float x = rp[0], y = rp[1], z = rp[2];
        float rn = sqrtf(x * x + y * y + z * z) + 1e-12f;
        x /= rn; y /= rn; z /= rn;
        const float* cp = C + ((size_t)bid * 64 + b) * 5;
        float cn = 0.f;
#pragma unroll
        for (int o = 0; o < 5; ++o) cn += cp[o] * cp[o];
        cn = sqrtf(cn);
        const float c1 = 0.4886025119029199f;
        const float c2 = 1.0925484305920792f;
        float Y[9];
        Y[0] = 0.28209479177387814f;
        Y[1] = c1 * y;
        Y[2] = c1 * z;
        Y[3] = c1 * x;
        Y[4] = c2 * x * y;
        Y[5] = c2 * y * z;
        Y[6] = 0.31539156525252005f * (3.f * z * z - 1.f);
        Y[7] = c2 * x * z;
        Y[8] = 0.5462742152960396f * (x * x - y * y);
#pragma unroll
        for (int k = 0; k < 9; ++k) s_coup[b][k] = Y[k] * cn;
    }
    __syncthreads();

    // H2[c][i] = sum_k coup[b][k] * cgc[k][i][seg[p]]   (c = b*5+p)
    const int seg[5] = {0, 0, 1, 2, 3};
    for (int o = tid; o < 2880; o += 512) {
        int c = o / 9, i = o % 9;
        int b = c / 5, p = c % 5;
        int pm = seg[p];
        float acc = 0.f;
#pragma unroll
        for (int k = 0; k < 9; ++k) acc += s_coup[b][k] * s_cgc[k * 81 + i * 9 + pm];
        s_H2[c][i] = acc;
    }
    __syncthreads();

    // coeff[r][i] = C[n,m,r] * sum_c SC[n][r][c] * H2[c][i]
    const float* scn = SC + (size_t)n * 320 * 320;
    const float* cb = C + (size_t)bid * 320;
    for (int o = tid; o < 2880; o += 512) {
        int r = o / 9, i = o % 9;
        const float* row = scn + (size_t)r * 320;
        float acc = 0.f;
#pragma unroll 4
        for (int c = 0; c < 320; ++c) acc += row[c] * s_H2[c][i];
        s_coeff[r][i] = acc * cb[r];
    }
    __syncthreads();

    // out[f][i] = sum_r coeff[r][i] * ao[n,m,r,f]   (r split in 2 halves)
    const int f = tid & 255;
    const int half = tid >> 8;
    const float* ap = ao + ((size_t)bid * 320 + half * 160) * 256 + f;
    const int rbase = half * 160;
    float acc[9];
#pragma unroll
    for (int i = 0; i < 9; ++i) acc[i] = 0.f;
#pragma unroll 8
    for (int r = 0; r < 160; ++r) {
        float v = ap[(size_t)r * 256];
        const float* cr = &s_coeff[rbase + r][0];
#pragma unroll
        for (int i = 0; i < 9; ++i) acc[i] += cr[i] * v;
    }
    if (half == 1) {
#pragma unroll
        for (int i = 0; i < 9; ++i) s_red[f][i] = acc[i];
    }
    __syncthreads();
    if (half == 0) {
        float* op = out + ((size_t)bid * 256 + f) * 9;
#pragma unroll
        for (int i = 0; i < 9; ++i) op[i] = acc[i] + s_red[f][i];
    }
}

extern "C" void kernel_launch(void* const* d_in, const int* in_sizes, int n_in,
                              void* d_out, int out_size, void* d_ws, size_t ws_size,
                              hipStream_t stream) {
    (void)in_sizes; (void)n_in; (void)out_size; (void)ws_size;
    const float* ao  = (const float*)d_in[0];
    const float* C   = (const float*)d_in[1];
    const float* S   = (const float*)d_in[2];
    const float* R   = (const float*)d_in[3];
    const float* wst = (const float*)d_in[4];
    const float* cgc = (const float*)d_in[5];
    float* out = (float*)d_out;
    float* SC = (float*)d_ws;   // 4 * 320 * 320 floats = 1.6 MB

    hipLaunchKernelGGL(k_sc, dim3(64), dim3(256), 0, stream, S, wst, SC);
    hipLaunchKernelGGL(k_main, dim3(256), dim3(512), 0, stream,
                       ao, C, R, cgc, SC, out);
}

// Round 5
// 35.012 us; speedup vs baseline: 2.1889x; 2.1889x over previous
//
#include <hip/hip_runtime.h>
#include <math.h>

// N=4, M=64, A=64, O=5, F=256
// Reduced algebra (post-filt structure):
//   Sc5 cols p=2,3,4 are identical (=M[.][2]); rows collapse to 3 variants u=min(o,2).
//   filt => u<2 rows only couple through g_u = M[u][0]+M[u][1] (paired with D0);
//           u=2 row only couples through gz = M[2][2] (paired with Dz).
//   G[n][u][b][a]: u<2 -> M[u][0]+M[u][1]; u=2 -> M[2][2]
//   coup[b][k] = Y_k(unit(R)) * ||C[b,:]||
//   D0[b][i] = sum_k coup[b][k]*cgc[k][i][0]
//   Dz[b][i] = sum_k coup[b][k]*(cgc[k][i][1]+cgc[k][i][2]+cgc[k][i][3])
//   W3[a][u][i] = sum_b G[n][u][b][a] * (u==2 ? Dz : D0)[b][i]
//   coeff[(a,o)][i] = C[a,o] * W3[a][min(o,2)][i]
//   out[nm][f][i] = sum_r coeff[r][i] * ao[nm][r][f]
//
// ws layout (floats):
//   G       off 0         : 4*3*64*64      = 49152  f
//   coeff   off 49152     : 256*320*9      = 737280 f
//   partial off 786432    : 512*2304       = 1179648 f

__global__ void k_sc(const float* __restrict__ S, const float* __restrict__ wst,
                     float* __restrict__ G) {
    int t = blockIdx.x * 256 + threadIdx.x;   // 16384 threads
    int n = t >> 12;
    int a = (t >> 6) & 63;   // row atom
    int b = t & 63;          // col atom
    float M[3][3];
#pragma unroll
    for (int x = 0; x < 3; ++x)
#pragma unroll
        for (int y = 0; y < 3; ++y)
            M[x][y] = S[(((n * 64 + a) * 3 + x) * 64 + b) * 3 + y];
#pragma unroll
    for (int it = 0; it < 5; ++it) {
        float w[3][3];
#pragma unroll
        for (int x = 0; x < 3; ++x)
#pragma unroll
            for (int y = 0; y < 3; ++y)
                w[x][y] = wst[it * 9 + x * 3 + y];
        float T[3][3];
#pragma unroll
        for (int x = 0; x < 3; ++x)
#pragma unroll
            for (int d = 0; d < 3; ++d)
                T[x][d] = w[x][0] * M[0][d] + w[x][1] * M[1][d] + w[x][2] * M[2][d];
#pragma unroll
        for (int x = 0; x < 3; ++x)
#pragma unroll
            for (int c = 0; c < 3; ++c) {
                float v = T[x][0] * w[c][0] + T[x][1] * w[c][1] + T[x][2] * w[c][2];
                M[x][c] = v / (1.f + expf(-v));   // swish
            }
    }
    // filt zeros: M[0][2], M[1][2], M[2][0], M[2][1]
    float g0 = M[0][0] + M[0][1];
    float g1 = M[1][0] + M[1][1];
    float gz = M[2][2];
    size_t base = (size_t)n * 12288 + (size_t)b * 64 + a;
    G[base]          = g0;
    G[base + 4096]   = g1;
    G[base + 8192]   = gz;
}

__global__ __launch_bounds__(512) void k_w3(
        const float* __restrict__ C, const float* __restrict__ R,
        const float* __restrict__ cgc, const float* __restrict__ G,
        float* __restrict__ coeff) {
    __shared__ float s_coup[64 * 9];
    __shared__ float s_D[2 * 9 * 64];   // [pm][i][b]
    __shared__ float s_W3[64 * 3 * 9];  // [a][u][i]

    const int nm = blockIdx.x;
    const int n = nm >> 6;
    const int tid = threadIdx.x;

    if (tid < 64) {
        const int b = tid;
        const float* rp = R + ((size_t)nm * 64 + b) * 3;
        float x = rp[0], y = rp[1], z = rp[2];
        float rn = sqrtf(x * x + y * y + z * z) + 1e-12f;
        x /= rn; y /= rn; z /= rn;
        const float* cp = C + ((size_t)nm * 64 + b) * 5;
        float cn = 0.f;
#pragma unroll
        for (int o = 0; o < 5; ++o) cn += cp[o] * cp[o];
        cn = sqrtf(cn);
        const float c1 = 0.4886025119029199f;
        const float c2 = 1.0925484305920792f;
        float Y[9];
        Y[0] = 0.28209479177387814f;
        Y[1] = c1 * y;
        Y[2] = c1 * z;
        Y[3] = c1 * x;
        Y[4] = c2 * x * y;
        Y[5] = c2 * y * z;
        Y[6] = 0.31539156525252005f * (3.f * z * z - 1.f);
        Y[7] = c2 * x * z;
        Y[8] = 0.5462742152960396f * (x * x - y * y);
#pragma unroll
        for (int k = 0; k < 9; ++k) s_coup[b * 9 + k] = Y[k] * cn;
    }
    __syncthreads();

    // D[pm][i][b] for all 576 (b,i) pairs with 512 threads (BUGFIX: strided loop)
    for (int e = tid; e < 576; e += 512) {
        const int b = e & 63, i = e >> 6;
        float d0 = 0.f, dz = 0.f;
#pragma unroll
        for (int k = 0; k < 9; ++k) {
            float cp = s_coup[b * 9 + k];
            const float* cg = cgc + k * 81 + i * 9;
            d0 = fmaf(cp, cg[0], d0);
            dz = fmaf(cp, cg[1] + cg[2] + cg[3], dz);
        }
        s_D[(0 * 9 + i) * 64 + b] = d0;
        s_D[(1 * 9 + i) * 64 + b] = dz;
    }
    __syncthreads();

    // W3[a][u][i] via wave-per-(u, i-triple); lane = a
    const int wid = __builtin_amdgcn_readfirstlane(tid >> 6);
    const int lane = tid & 63;   // a
    for (int pp = wid; pp < 9; pp += 8) {
        const int u = pp / 3;
        const int i0 = (pp % 3) * 3;
        const int pm = (u == 2) ? 1 : 0;
        const float* gp = G + (size_t)n * 12288 + (size_t)u * 4096 + lane;  // + b*64
        const float* dp = &s_D[(pm * 9 + i0) * 64];                          // + b
        float a0 = 0.f, a1 = 0.f, a2 = 0.f;
#pragma unroll 8
        for (int b = 0; b < 64; ++b) {
            float g = gp[b * 64];          // coalesced over lane=a
            a0 = fmaf(g, dp[b], a0);       // broadcast LDS reads (uniform addr)
            a1 = fmaf(g, dp[64 + b], a1);
            a2 = fmaf(g, dp[128 + b], a2);
        }
        s_W3[(lane * 3 + u) * 9 + i0 + 0] = a0;
        s_W3[(lane * 3 + u) * 9 + i0 + 1] = a1;
        s_W3[(lane * 3 + u) * 9 + i0 + 2] = a2;
    }
    __syncthreads();

    // coeff[(a*5+o)][i] = C[a,o] * W3[a][min(o,2)][i]
    const float* Cb = C + (size_t)nm * 320;
    float* cf = coeff + (size_t)nm * 320 * 9;
    for (int e = tid; e < 2880; e += 512) {
        int a = e / 45;
        int rem = e - a * 45;
        int o = rem / 9;
        int i = rem - o * 9;
        int u = o < 2 ? o : 2;
        cf[e] = Cb[a * 5 + o] * s_W3[(a * 3 + u) * 9 + i];
    }
}

__global__ __launch_bounds__(512) void k_out(
        const float* __restrict__ ao, const float* __restrict__ coeff,
        float* __restrict__ partial) {
    __shared__ float s_red[256 * 9];
    const int bid = blockIdx.x;          // nm*2 + ch
    const int nm = bid >> 1;
    const int ch = bid & 1;
    const int tid = threadIdx.x;
    const int f = tid & 255;
    const int h = __builtin_amdgcn_readfirstlane(tid >> 8);
    const int rbase = ch * 160 + h * 80;
    const float* ap = ao + ((size_t)nm * 320 + rbase) * 256 + f;
    const float* cf = coeff + ((size_t)nm * 320 + rbase) * 9;   // wave-uniform base
    float acc[9];
#pragma unroll
    for (int i = 0; i < 9; ++i) acc[i] = 0.f;
#pragma unroll 8
    for (int r = 0; r < 80; ++r) {
        float v = ap[(size_t)r * 256];
#pragma unroll
        for (int i = 0; i < 9; ++i) acc[i] = fmaf(cf[r * 9 + i], v, acc[i]);
    }
    if (tid >= 256) {
#pragma unroll
        for (int i = 0; i < 9; ++i) s_red[f * 9 + i] = acc[i];
    }
    __syncthreads();
    if (tid < 256) {
        float* pp = partial + (size_t)bid * 2304 + f * 9;
#pragma unroll
        for (int i = 0; i < 9; ++i) pp[i] = acc[i] + s_red[f * 9 + i];
    }
}

__global__ void k_red(const float* __restrict__ partial, float* __restrict__ out) {
    int e = blockIdx.x * 256 + threadIdx.x;   // < 589824
    int nm = e / 2304;
    int j = e - nm * 2304;
    out[e] = partial[(size_t)(nm * 2) * 2304 + j] +
             partial[(size_t)(nm * 2 + 1) * 2304 + j];
}

extern "C" void kernel_launch(void* const* d_in, const int* in_sizes, int n_in,
                              void* d_out, int out_size, void* d_ws, size_t ws_size,
                              hipStream_t stream) {
    (void)in_sizes; (void)n_in; (void)out_size; (void)ws_size;
    const float* ao  = (const float*)d_in[0];
    const float* C   = (const float*)d_in[1];
    const float* S   = (const float*)d_in[2];
    const float* R   = (const float*)d_in[3];
    const float* wst = (const float*)d_in[4];
    const float* cgc = (const float*)d_in[5];
    float* out = (float*)d_out;
    float* ws = (float*)d_ws;
    float* G       = ws;             // 49152 floats
    float* coeff   = ws + 49152;     // 737280 floats
    float* partial = ws + 786432;    // 1179648 floats

    hipLaunchKernelGGL(k_sc,  dim3(64),   dim3(256), 0, stream, S, wst, G);
    hipLaunchKernelGGL(k_w3,  dim3(256),  dim3(512), 0, stream, C, R, cgc, G, coeff);
    hipLaunchKernelGGL(k_out, dim3(512),  dim3(512), 0, stream, ao, coeff, partial);
    hipLaunchKernelGGL(k_red, dim3(2304), dim3(256), 0, stream, partial, out);
}

// Round 6
// 33.923 us; speedup vs baseline: 2.2591x; 1.0321x over previous
//
#include <hip/hip_runtime.h>
#include <math.h>

// N=4, M=64, A=64, O=5, F=256
// Reduced algebra (post-filt structure):
//   G[n][u][b][a]: u<2 -> M[u][0]+M[u][1]; u=2 -> M[2][2]   (M = 5x bilinear+swish of S)
//   coup[b][k] = Y_k(unit(R)) * ||C[b,:]||
//   D0[b][i] = sum_k coup[b][k]*cgc[k][i][0]
//   Dz[b][i] = sum_k coup[b][k]*(cgc[k][i][1]+cgc[k][i][2]+cgc[k][i][3])
//   W3[a][u][i] = sum_b G[n][u][b][a] * (u==2 ? Dz : D0)[b][i]
//   coeff[(a,o)][i] = C[a,o] * W3[a][min(o,2)][i]
//   out[nm][f][i] = sum_r coeff[r][i] * ao[nm][r][f]
//
// ws layout (floats):
//   G       off 0      : 4*3*64*64 = 49152  f
//   coeff   off 49152  : 256*320*9 = 737280 f

__global__ void k_sc(const float* __restrict__ S, const float* __restrict__ wst,
                     float* __restrict__ G) {
    int t = blockIdx.x * 256 + threadIdx.x;   // 16384 threads
    int n = t >> 12;
    int a = (t >> 6) & 63;   // row atom
    int b = t & 63;          // col atom
    float M[3][3];
#pragma unroll
    for (int x = 0; x < 3; ++x)
#pragma unroll
        for (int y = 0; y < 3; ++y)
            M[x][y] = S[(((n * 64 + a) * 3 + x) * 64 + b) * 3 + y];
#pragma unroll
    for (int it = 0; it < 5; ++it) {
        float w[3][3];
#pragma unroll
        for (int x = 0; x < 3; ++x)
#pragma unroll
            for (int y = 0; y < 3; ++y)
                w[x][y] = wst[it * 9 + x * 3 + y];
        float T[3][3];
#pragma unroll
        for (int x = 0; x < 3; ++x)
#pragma unroll
            for (int d = 0; d < 3; ++d)
                T[x][d] = w[x][0] * M[0][d] + w[x][1] * M[1][d] + w[x][2] * M[2][d];
#pragma unroll
        for (int x = 0; x < 3; ++x)
#pragma unroll
            for (int c = 0; c < 3; ++c) {
                float v = T[x][0] * w[c][0] + T[x][1] * w[c][1] + T[x][2] * w[c][2];
                M[x][c] = v / (1.f + expf(-v));   // swish
            }
    }
    float g0 = M[0][0] + M[0][1];
    float g1 = M[1][0] + M[1][1];
    float gz = M[2][2];
    size_t base = (size_t)n * 12288 + (size_t)b * 64 + a;
    G[base]          = g0;
    G[base + 4096]   = g1;
    G[base + 8192]   = gz;
}

__global__ __launch_bounds__(512) void k_w3(
        const float* __restrict__ C, const float* __restrict__ R,
        const float* __restrict__ cgc, const float* __restrict__ G,
        float* __restrict__ coeff) {
    __shared__ float s_coup[64 * 9];
    __shared__ float s_D[2 * 9 * 64];   // [pm][i][b]
    __shared__ float s_W3[64 * 3 * 9];  // [a][u][i]

    const int nm = blockIdx.x;
    const int n = nm >> 6;
    const int tid = threadIdx.x;

    if (tid < 64) {
        const int b = tid;
        const float* rp = R + ((size_t)nm * 64 + b) * 3;
        float x = rp[0], y = rp[1], z = rp[2];
        float rn = sqrtf(x * x + y * y + z * z) + 1e-12f;
        x /= rn; y /= rn; z /= rn;
        const float* cp = C + ((size_t)nm * 64 + b) * 5;
        float cn = 0.f;
#pragma unroll
        for (int o = 0; o < 5; ++o) cn += cp[o] * cp[o];
        cn = sqrtf(cn);
        const float c1 = 0.4886025119029199f;
        const float c2 = 1.0925484305920792f;
        float Y[9];
        Y[0] = 0.28209479177387814f;
        Y[1] = c1 * y;
        Y[2] = c1 * z;
        Y[3] = c1 * x;
        Y[4] = c2 * x * y;
        Y[5] = c2 * y * z;
        Y[6] = 0.31539156525252005f * (3.f * z * z - 1.f);
        Y[7] = c2 * x * z;
        Y[8] = 0.5462742152960396f * (x * x - y * y);
#pragma unroll
        for (int k = 0; k < 9; ++k) s_coup[b * 9 + k] = Y[k] * cn;
    }
    __syncthreads();

    // D[pm][i][b] for all 576 (b,i) pairs (strided: 512 threads)
    for (int e = tid; e < 576; e += 512) {
        const int b = e & 63, i = e >> 6;
        float d0 = 0.f, dz = 0.f;
#pragma unroll
        for (int k = 0; k < 9; ++k) {
            float cp = s_coup[b * 9 + k];
            const float* cg = cgc + k * 81 + i * 9;
            d0 = fmaf(cp, cg[0], d0);
            dz = fmaf(cp, cg[1] + cg[2] + cg[3], dz);
        }
        s_D[(0 * 9 + i) * 64 + b] = d0;
        s_D[(1 * 9 + i) * 64 + b] = dz;
    }
    __syncthreads();

    // W3[a][u][i] via wave-per-(u, i-triple); lane = a
    const int wid = __builtin_amdgcn_readfirstlane(tid >> 6);
    const int lane = tid & 63;   // a
    for (int pp = wid; pp < 9; pp += 8) {
        const int u = pp / 3;
        const int i0 = (pp % 3) * 3;
        const int pm = (u == 2) ? 1 : 0;
        const float* gp = G + (size_t)n * 12288 + (size_t)u * 4096 + lane;  // + b*64
        const float* dp = &s_D[(pm * 9 + i0) * 64];                          // + b
        float a0 = 0.f, a1 = 0.f, a2 = 0.f;
#pragma unroll 8
        for (int b = 0; b < 64; ++b) {
            float g = gp[b * 64];          // coalesced over lane=a
            a0 = fmaf(g, dp[b], a0);       // broadcast LDS reads (uniform addr)
            a1 = fmaf(g, dp[64 + b], a1);
            a2 = fmaf(g, dp[128 + b], a2);
        }
        s_W3[(lane * 3 + u) * 9 + i0 + 0] = a0;
        s_W3[(lane * 3 + u) * 9 + i0 + 1] = a1;
        s_W3[(lane * 3 + u) * 9 + i0 + 2] = a2;
    }
    __syncthreads();

    // coeff[(a*5+o)][i] = C[a,o] * W3[a][min(o,2)][i]
    const float* Cb = C + (size_t)nm * 320;
    float* cf = coeff + (size_t)nm * 320 * 9;
    for (int e = tid; e < 2880; e += 512) {
        int a = e / 45;
        int rem = e - a * 45;
        int o = rem / 9;
        int i = rem - o * 9;
        int u = o < 2 ? o : 2;
        cf[e] = Cb[a * 5 + o] * s_W3[(a * 3 + u) * 9 + i];
    }
}

// One block per (nm, f-half). All 320 r inside the block: 4 wave-uniform
// r-chunks of 80, LDS tree-reduce, direct write to out. No partial buffer.
__global__ __launch_bounds__(512) void k_out(
        const float* __restrict__ ao, const float* __restrict__ coeff,
        float* __restrict__ out) {
    __shared__ float s_red[3 * 128 * 9];
    const int bid = blockIdx.x;          // nm*2 + fh
    const int nm = bid >> 1;
    const int fh = bid & 1;
    const int tid = threadIdx.x;
    const int fl = tid & 127;            // f-lane within half
    const int f = fh * 128 + fl;
    const int rq = __builtin_amdgcn_readfirstlane(tid >> 7);  // 0..3, wave-uniform
    const int rbase = rq * 80;
    const float* ap = ao + ((size_t)nm * 320 + rbase) * 256 + f;
    const float* cf = coeff + ((size_t)nm * 320 + rbase) * 9;   // wave-uniform base
    float acc[9];
#pragma unroll
    for (int i = 0; i < 9; ++i) acc[i] = 0.f;
#pragma unroll 8
    for (int r = 0; r < 80; ++r) {
        float v = ap[(size_t)r * 256];
#pragma unroll
        for (int i = 0; i < 9; ++i) acc[i] = fmaf(cf[r * 9 + i], v, acc[i]);
    }
    if (rq > 0) {
        float* sp = &s_red[((rq - 1) * 128 + fl) * 9];
#pragma unroll
        for (int i = 0; i < 9; ++i) sp[i] = acc[i];
    }
    __syncthreads();
    if (rq == 0) {
        float* op = out + ((size_t)nm * 256 + f) * 9;
#pragma unroll
        for (int i = 0; i < 9; ++i)
            op[i] = acc[i] + s_red[(0 * 128 + fl) * 9 + i]
                           + s_red[(1 * 128 + fl) * 9 + i]
                           + s_red[(2 * 128 + fl) * 9 + i];
    }
}

extern "C" void kernel_launch(void* const* d_in, const int* in_sizes, int n_in,
                              void* d_out, int out_size, void* d_ws, size_t ws_size,
                              hipStream_t stream) {
    (void)in_sizes; (void)n_in; (void)out_size; (void)ws_size;
    const float* ao  = (const float*)d_in[0];
    const float* C   = (const float*)d_in[1];
    const float* S   = (const float*)d_in[2];
    const float* R   = (const float*)d_in[3];
    const float* wst = (const float*)d_in[4];
    const float* cgc = (const float*)d_in[5];
    float* out = (float*)d_out;
    float* ws = (float*)d_ws;
    float* G     = ws;             // 49152 floats
    float* coeff = ws + 49152;     // 737280 floats

    hipLaunchKernelGGL(k_sc,  dim3(64),  dim3(256), 0, stream, S, wst, G);
    hipLaunchKernelGGL(k_w3,  dim3(256), dim3(512), 0, stream, C, R, cgc, G, coeff);
    hipLaunchKernelGGL(k_out, dim3(512), dim3(512), 0, stream, ao, coeff, out);
}

// Round 7
// 33.674 us; speedup vs baseline: 2.2758x; 1.0074x over previous
//
#include <hip/hip_runtime.h>
#include <math.h>

// N=4, M=64, A=64, O=5, F=256
// Reduced algebra (post-filt structure):
//   G[n][u][b][a]: u<2 -> M[u][0]+M[u][1]; u=2 -> M[2][2]   (M = 5x bilinear+swish of S)
//   coup[b][k] = Y_k(unit(R)) * ||C[b,:]||
//   D0[b][i] = sum_k coup[b][k]*cgc[k][i][0]
//   Dz[b][i] = sum_k coup[b][k]*(cgc[k][i][1]+cgc[k][i][2]+cgc[k][i][3])
//   W3[a][u][i] = sum_b G[n][u][b][a] * (u==2 ? Dz : D0)[b][i]
//   coeff[(a,o)][i] = C[a,o] * W3[a][min(o,2)][i]
//   out[nm][f][i] = sum_r coeff[r][i] * ao[nm][r][f]
//
// ws layout (floats): G off 0 (49152 f), coeff off 49152 (737280 f)

__global__ void k_sc(const float* __restrict__ S, const float* __restrict__ wst,
                     float* __restrict__ G) {
    int t = blockIdx.x * 128 + threadIdx.x;   // 16384 threads over 128 blocks
    int n = t >> 12;
    int a = (t >> 6) & 63;   // row atom
    int b = t & 63;          // col atom
    float M[3][3];
#pragma unroll
    for (int x = 0; x < 3; ++x)
#pragma unroll
        for (int y = 0; y < 3; ++y)
            M[x][y] = S[(((n * 64 + a) * 3 + x) * 64 + b) * 3 + y];
#pragma unroll
    for (int it = 0; it < 5; ++it) {
        float w[3][3];
#pragma unroll
        for (int x = 0; x < 3; ++x)
#pragma unroll
            for (int y = 0; y < 3; ++y)
                w[x][y] = wst[it * 9 + x * 3 + y];
        float T[3][3];
#pragma unroll
        for (int x = 0; x < 3; ++x)
#pragma unroll
            for (int d = 0; d < 3; ++d)
                T[x][d] = w[x][0] * M[0][d] + w[x][1] * M[1][d] + w[x][2] * M[2][d];
#pragma unroll
        for (int x = 0; x < 3; ++x)
#pragma unroll
            for (int c = 0; c < 3; ++c) {
                float v = T[x][0] * w[c][0] + T[x][1] * w[c][1] + T[x][2] * w[c][2];
                M[x][c] = v / (1.f + expf(-v));   // swish
            }
    }
    float g0 = M[0][0] + M[0][1];
    float g1 = M[1][0] + M[1][1];
    float gz = M[2][2];
    size_t base = (size_t)n * 12288 + (size_t)b * 64 + a;
    G[base]          = g0;
    G[base + 4096]   = g1;
    G[base + 8192]   = gz;
}

// 576 threads = 9 waves: one W3 task per wave (no double duty).
__global__ __launch_bounds__(576) void k_w3(
        const float* __restrict__ C, const float* __restrict__ R,
        const float* __restrict__ cgc, const float* __restrict__ G,
        float* __restrict__ coeff) {
    __shared__ float s_coup[64 * 9];
    __shared__ float s_D[2 * 9 * 64];   // [pm][i][b]
    __shared__ float s_W3[64 * 3 * 9];  // [a][u][i]

    const int nm = blockIdx.x;
    const int n = nm >> 6;
    const int tid = threadIdx.x;

    if (tid < 64) {
        const int b = tid;
        const float* rp = R + ((size_t)nm * 64 + b) * 3;
        float x = rp[0], y = rp[1], z = rp[2];
        float rn = sqrtf(x * x + y * y + z * z) + 1e-12f;
        x /= rn; y /= rn; z /= rn;
        const float* cp = C + ((size_t)nm * 64 + b) * 5;
        float cn = 0.f;
#pragma unroll
        for (int o = 0; o < 5; ++o) cn += cp[o] * cp[o];
        cn = sqrtf(cn);
        const float c1 = 0.4886025119029199f;
        const float c2 = 1.0925484305920792f;
        float Y[9];
        Y[0] = 0.28209479177387814f;
        Y[1] = c1 * y;
        Y[2] = c1 * z;
        Y[3] = c1 * x;
        Y[4] = c2 * x * y;
        Y[5] = c2 * y * z;
        Y[6] = 0.31539156525252005f * (3.f * z * z - 1.f);
        Y[7] = c2 * x * z;
        Y[8] = 0.5462742152960396f * (x * x - y * y);
#pragma unroll
        for (int k = 0; k < 9; ++k) s_coup[b * 9 + k] = Y[k] * cn;
    }
    __syncthreads();

    // D[pm][i][b]: exactly 576 (b,i) pairs, one per thread
    {
        const int b = tid & 63, i = tid >> 6;
        float d0 = 0.f, dz = 0.f;
#pragma unroll
        for (int k = 0; k < 9; ++k) {
            float cp = s_coup[b * 9 + k];
            const float* cg = cgc + k * 81 + i * 9;
            d0 = fmaf(cp, cg[0], d0);
            dz = fmaf(cp, cg[1] + cg[2] + cg[3], dz);
        }
        s_D[(0 * 9 + i) * 64 + b] = d0;
        s_D[(1 * 9 + i) * 64 + b] = dz;
    }
    __syncthreads();

    // W3[a][u][i]: wave pp = (u, i-triple); lane = a
    const int pp = __builtin_amdgcn_readfirstlane(tid >> 6);  // 0..8
    const int lane = tid & 63;   // a
    {
        const int u = pp / 3;
        const int i0 = (pp % 3) * 3;
        const int pm = (u == 2) ? 1 : 0;
        const float* gp = G + (size_t)n * 12288 + (size_t)u * 4096 + lane;  // + b*64
        const float* dp = &s_D[(pm * 9 + i0) * 64];                          // + b
        float a0 = 0.f, a1 = 0.f, a2 = 0.f;
#pragma unroll 8
        for (int b = 0; b < 64; ++b) {
            float g = gp[b * 64];          // coalesced over lane=a
            a0 = fmaf(g, dp[b], a0);       // broadcast LDS reads (uniform addr)
            a1 = fmaf(g, dp[64 + b], a1);
            a2 = fmaf(g, dp[128 + b], a2);
        }
        s_W3[(lane * 3 + u) * 9 + i0 + 0] = a0;
        s_W3[(lane * 3 + u) * 9 + i0 + 1] = a1;
        s_W3[(lane * 3 + u) * 9 + i0 + 2] = a2;
    }
    __syncthreads();

    // coeff[(a*5+o)][i] = C[a,o] * W3[a][min(o,2)][i]
    const float* Cb = C + (size_t)nm * 320;
    float* cf = coeff + (size_t)nm * 320 * 9;
    for (int e = tid; e < 2880; e += 576) {
        int a = e / 45;
        int rem = e - a * 45;
        int o = rem / 9;
        int i = rem - o * 9;
        int u = o < 2 ? o : 2;
        cf[e] = Cb[a * 5 + o] * s_W3[(a * 3 + u) * 9 + i];
    }
}

// Block = (nm, f-half of 128). 8 waves, each owns a 40-r chunk and covers all
// 128 f via float2 (8 B/lane). Full 8-way LDS reduce by all 512 threads.
__global__ __launch_bounds__(512) void k_out(
        const float* __restrict__ ao, const float* __restrict__ coeff,
        float* __restrict__ out) {
    __shared__ float s_par[8][128 * 9];   // 36.9 KB
    const int bid = blockIdx.x;          // nm*2 + fh
    const int nm = bid >> 1;
    const int fh = bid & 1;
    const int tid = threadIdx.x;
    const int lane = tid & 63;
    const int w = __builtin_amdgcn_readfirstlane(tid >> 6);  // 0..7
    const int rbase = w * 40;
    const float* ap = ao + ((size_t)nm * 320 + rbase) * 256 + fh * 128 + lane * 2;
    const float* cf = coeff + ((size_t)nm * 320 + rbase) * 9;   // wave-uniform
    float acc[9][2];
#pragma unroll
    for (int i = 0; i < 9; ++i) { acc[i][0] = 0.f; acc[i][1] = 0.f; }
#pragma unroll 8
    for (int r = 0; r < 40; ++r) {
        float2 v = *reinterpret_cast<const float2*>(ap + (size_t)r * 256);
#pragma unroll
        for (int i = 0; i < 9; ++i) {
            float c = cf[r * 9 + i];      // wave-uniform scalar load
            acc[i][0] = fmaf(c, v.x, acc[i][0]);
            acc[i][1] = fmaf(c, v.y, acc[i][1]);
        }
    }
#pragma unroll
    for (int j = 0; j < 2; ++j)
#pragma unroll
        for (int i = 0; i < 9; ++i)
            s_par[w][(lane * 2 + j) * 9 + i] = acc[i][j];
    __syncthreads();
    // 1152 (f-local, i) slots; coalesced read + coalesced out write
    for (int s = tid; s < 1152; s += 512) {
        float sum = 0.f;
#pragma unroll
        for (int w2 = 0; w2 < 8; ++w2) sum += s_par[w2][s];
        out[(size_t)nm * 2304 + fh * 1152 + s] = sum;
    }
}

extern "C" void kernel_launch(void* const* d_in, const int* in_sizes, int n_in,
                              void* d_out, int out_size, void* d_ws, size_t ws_size,
                              hipStream_t stream) {
    (void)in_sizes; (void)n_in; (void)out_size; (void)ws_size;
    const float* ao  = (const float*)d_in[0];
    const float* C   = (const float*)d_in[1];
    const float* S   = (const float*)d_in[2];
    const float* R   = (const float*)d_in[3];
    const float* wst = (const float*)d_in[4];
    const float* cgc = (const float*)d_in[5];
    float* out = (float*)d_out;
    float* ws = (float*)d_ws;
    float* G     = ws;             // 49152 floats
    float* coeff = ws + 49152;     // 737280 floats

    hipLaunchKernelGGL(k_sc,  dim3(128), dim3(128), 0, stream, S, wst, G);
    hipLaunchKernelGGL(k_w3,  dim3(256), dim3(576), 0, stream, C, R, cgc, G, coeff);
    hipLaunchKernelGGL(k_out, dim3(512), dim3(512), 0, stream, ao, coeff, out);
}

// Round 8
// 31.570 us; speedup vs baseline: 2.4275x; 1.0666x over previous
//
#include <hip/hip_runtime.h>
#include <math.h>

// N=4, M=64, A=64, O=5, F=256
// Reduced algebra (post-filt structure):
//   G[n][u][b][a]: u<2 -> M[u][0]+M[u][1]; u=2 -> M[2][2]   (M = 5x bilinear+swish of S)
//   coup[b][k] = Y_k(unit(R)) * ||C[b,:]||
//   D0[b][i] = sum_k coup[b][k]*cgc[k][i][0]
//   Dz[b][i] = sum_k coup[b][k]*(cgc[k][i][1]+cgc[k][i][2]+cgc[k][i][3])
//   W3[nm][a][u][i] = sum_b G[n][u][b][a] * (u==2 ? Dz : D0)[b][i]
//   out[nm][f][i] = sum_a  W3[a][0][i]*(C[a,0]*ao[a,0,f])
//                        + W3[a][1][i]*(C[a,1]*ao[a,1,f])
//                        + W3[a][2][i]*(C[a,2]*ao[a,2,f]+C[a,3]*ao[a,3,f]+C[a,4]*ao[a,4,f])
//
// ws layout (floats): G off 0 (49152 f), W3 off 49152 (256*1792 = 458752 f, rows padded 27->28)

typedef float v4f __attribute__((ext_vector_type(4)));
static __device__ inline v4f splat4(float s) { return (v4f){s, s, s, s}; }

__global__ void k_sc(const float* __restrict__ S, const float* __restrict__ wst,
                     float* __restrict__ G) {
    int t = blockIdx.x * 128 + threadIdx.x;   // 16384 threads over 128 blocks
    int n = t >> 12;
    int a = (t >> 6) & 63;   // row atom
    int b = t & 63;          // col atom
    float M[3][3];
#pragma unroll
    for (int x = 0; x < 3; ++x)
#pragma unroll
        for (int y = 0; y < 3; ++y)
            M[x][y] = S[(((n * 64 + a) * 3 + x) * 64 + b) * 3 + y];
#pragma unroll
    for (int it = 0; it < 5; ++it) {
        float w[3][3];
#pragma unroll
        for (int x = 0; x < 3; ++x)
#pragma unroll
            for (int y = 0; y < 3; ++y)
                w[x][y] = wst[it * 9 + x * 3 + y];
        float T[3][3];
#pragma unroll
        for (int x = 0; x < 3; ++x)
#pragma unroll
            for (int d = 0; d < 3; ++d)
                T[x][d] = w[x][0] * M[0][d] + w[x][1] * M[1][d] + w[x][2] * M[2][d];
#pragma unroll
        for (int x = 0; x < 3; ++x)
#pragma unroll
            for (int c = 0; c < 3; ++c) {
                float v = T[x][0] * w[c][0] + T[x][1] * w[c][1] + T[x][2] * w[c][2];
                M[x][c] = v / (1.f + expf(-v));   // swish
            }
    }
    float g0 = M[0][0] + M[0][1];
    float g1 = M[1][0] + M[1][1];
    float gz = M[2][2];
    size_t base = (size_t)n * 12288 + (size_t)b * 64 + a;
    G[base]          = g0;
    G[base + 4096]   = g1;
    G[base + 8192]   = gz;
}

// 576 threads = 9 waves: one W3 task per wave.
__global__ __launch_bounds__(576) void k_w3(
        const float* __restrict__ C, const float* __restrict__ R,
        const float* __restrict__ cgc, const float* __restrict__ G,
        float* __restrict__ wsW3) {
    __shared__ float s_coup[64 * 9];
    __shared__ float s_D[2 * 9 * 64];   // [pm][i][b]
    __shared__ float s_W3[64 * 27];     // [a][u][i]

    const int nm = blockIdx.x;
    const int n = nm >> 6;
    const int tid = threadIdx.x;

    if (tid < 64) {
        const int b = tid;
        const float* rp = R + ((size_t)nm * 64 + b) * 3;
        float x = rp[0], y = rp[1], z = rp[2];
        float rn = sqrtf(x * x + y * y + z * z) + 1e-12f;
        x /= rn; y /= rn; z /= rn;
        const float* cp = C + ((size_t)nm * 64 + b) * 5;
        float cn = 0.f;
#pragma unroll
        for (int o = 0; o < 5; ++o) cn += cp[o] * cp[o];
        cn = sqrtf(cn);
        const float c1 = 0.4886025119029199f;
        const float c2 = 1.0925484305920792f;
        float Y[9];
        Y[0] = 0.28209479177387814f;
        Y[1] = c1 * y;
        Y[2] = c1 * z;
        Y[3] = c1 * x;
        Y[4] = c2 * x * y;
        Y[5] = c2 * y * z;
        Y[6] = 0.31539156525252005f * (3.f * z * z - 1.f);
        Y[7] = c2 * x * z;
        Y[8] = 0.5462742152960396f * (x * x - y * y);
#pragma unroll
        for (int k = 0; k < 9; ++k) s_coup[b * 9 + k] = Y[k] * cn;
    }
    __syncthreads();

    // D[pm][i][b]: exactly 576 (b,i) pairs, one per thread
    {
        const int b = tid & 63, i = tid >> 6;
        float d0 = 0.f, dz = 0.f;
#pragma unroll
        for (int k = 0; k < 9; ++k) {
            float cp = s_coup[b * 9 + k];
            const float* cg = cgc + k * 81 + i * 9;
            d0 = fmaf(cp, cg[0], d0);
            dz = fmaf(cp, cg[1] + cg[2] + cg[3], dz);
        }
        s_D[(0 * 9 + i) * 64 + b] = d0;
        s_D[(1 * 9 + i) * 64 + b] = dz;
    }
    __syncthreads();

    // W3[a][u][i]: wave pp = (u, i-triple); lane = a
    const int pp = __builtin_amdgcn_readfirstlane(tid >> 6);  // 0..8
    const int lane = tid & 63;   // a
    {
        const int u = pp / 3;
        const int i0 = (pp % 3) * 3;
        const int pm = (u == 2) ? 1 : 0;
        const float* gp = G + (size_t)n * 12288 + (size_t)u * 4096 + lane;  // + b*64
        const float* dp = &s_D[(pm * 9 + i0) * 64];                          // + b
        float a0 = 0.f, a1 = 0.f, a2 = 0.f;
#pragma unroll 8
        for (int b = 0; b < 64; ++b) {
            float g = gp[b * 64];          // coalesced over lane=a
            a0 = fmaf(g, dp[b], a0);       // broadcast LDS reads (uniform addr)
            a1 = fmaf(g, dp[64 + b], a1);
            a2 = fmaf(g, dp[128 + b], a2);
        }
        s_W3[lane * 27 + u * 9 + i0 + 0] = a0;
        s_W3[lane * 27 + u * 9 + i0 + 1] = a1;
        s_W3[lane * 27 + u * 9 + i0 + 2] = a2;
    }
    __syncthreads();

    // export padded [a][28]
    float* wp = wsW3 + (size_t)nm * 1792;
    for (int e = tid; e < 1792; e += 576) {
        int a = e / 28, q = e - a * 28;
        wp[e] = (q < 27) ? s_W3[a * 27 + q] : 0.f;
    }
}

// Block = nm (256 blocks, 512 threads). Wave w owns f-window [w*32, w*32+32);
// lane: fgrp = lane&7 -> f0 = w*32+fgrp*4 (float4), agrp = lane>>3 -> a = agrp+8t.
// All coefficients in LDS (broadcast ds_read); no SMEM/uniform loads in loop.
// Cross-agrp reduce via shfl_xor; agrp==0 lanes store 36 floats (16B-aligned).
__global__ __launch_bounds__(512) void k_out(
        const float* __restrict__ ao, const float* __restrict__ C,
        const float* __restrict__ wsW3, float* __restrict__ out) {
    __shared__ float s_W3[64 * 28];   // padded rows, 7 KB
    __shared__ float s_C[320];
    const int nm = blockIdx.x;
    const int tid = threadIdx.x;
    {
        const float* wp = wsW3 + (size_t)nm * 1792;
        for (int e = tid; e < 1792; e += 512) s_W3[e] = wp[e];
        const float* cp = C + (size_t)nm * 320;
        for (int e = tid; e < 320; e += 512) s_C[e] = cp[e];
    }
    __syncthreads();

    const int w = tid >> 6;
    const int lane = tid & 63;
    const int fgrp = lane & 7;
    const int agrp = lane >> 3;
    const int f0 = w * 32 + fgrp * 4;
    const float* ap = ao + (size_t)nm * 81920 + (size_t)agrp * 1280 + f0;

    v4f acc[9];
#pragma unroll
    for (int i = 0; i < 9; ++i) acc[i] = splat4(0.f);

#pragma unroll
    for (int t = 0; t < 8; ++t) {
        const int a = agrp + 8 * t;
        const float* aop = ap + t * 10240;
        v4f v0 = *(const v4f*)(aop + 0 * 256);
        v4f v1 = *(const v4f*)(aop + 1 * 256);
        v4f v2 = *(const v4f*)(aop + 2 * 256);
        v4f v3 = *(const v4f*)(aop + 3 * 256);
        v4f v4 = *(const v4f*)(aop + 4 * 256);
        const float* cc = &s_C[a * 5];
        v4f e0 = splat4(cc[0]) * v0;
        v4f e1 = splat4(cc[1]) * v1;
        v4f e2 = splat4(cc[2]) * v2 + splat4(cc[3]) * v3 + splat4(cc[4]) * v4;
        const float* w3 = &s_W3[a * 28];
#pragma unroll
        for (int i = 0; i < 9; ++i)
            acc[i] += splat4(w3[i]) * e0 + splat4(w3[9 + i]) * e1 + splat4(w3[18 + i]) * e2;
    }

    // reduce over the 8 agrp groups (lanes xor 8,16,32)
#pragma unroll
    for (int mask = 8; mask <= 32; mask <<= 1) {
#pragma unroll
        for (int i = 0; i < 9; ++i) {
#pragma unroll
            for (int j = 0; j < 4; ++j)
                acc[i][j] += __shfl_xor(acc[i][j], mask, 64);
        }
    }

    if (agrp == 0) {
        v4f buf4[9];
        float* bp = (float*)buf4;
#pragma unroll
        for (int j = 0; j < 4; ++j)
#pragma unroll
            for (int i = 0; i < 9; ++i)
                bp[j * 9 + i] = acc[i][j];
        float* op = out + (size_t)nm * 2304 + (size_t)f0 * 9;   // 16B-aligned
#pragma unroll
        for (int q = 0; q < 9; ++q)
            *(v4f*)(op + q * 4) = buf4[q];
    }
}

extern "C" void kernel_launch(void* const* d_in, const int* in_sizes, int n_in,
                              void* d_out, int out_size, void* d_ws, size_t ws_size,
                              hipStream_t stream) {
    (void)in_sizes; (void)n_in; (void)out_size; (void)ws_size;
    const float* ao  = (const float*)d_in[0];
    const float* C   = (const float*)d_in[1];
    const float* S   = (const float*)d_in[2];
    const float* R   = (const float*)d_in[3];
    const float* wst = (const float*)d_in[4];
    const float* cgc = (const float*)d_in[5];
    float* out = (float*)d_out;
    float* ws = (float*)d_ws;
    float* G    = ws;             // 49152 floats
    float* wsW3 = ws + 49152;     // 458752 floats

    hipLaunchKernelGGL(k_sc,  dim3(128), dim3(128), 0, stream, S, wst, G);
    hipLaunchKernelGGL(k_w3,  dim3(256), dim3(576), 0, stream, C, R, cgc, G, wsW3);
    hipLaunchKernelGGL(k_out, dim3(256), dim3(512), 0, stream, ao, C, wsW3, out);
}